// Round 14
// baseline (455.752 us; speedup 1.0000x reference)
//
#include <hip/hip_runtime.h>
#include <cstdint>
#include <cstddef>

typedef unsigned short u16;
typedef unsigned int u32;

typedef unsigned short u16x8 __attribute__((ext_vector_type(8)));
typedef __bf16 bf16x8 __attribute__((ext_vector_type(8)));
typedef float f32x4 __attribute__((ext_vector_type(4)));
typedef float f32x8 __attribute__((ext_vector_type(8)));

#define NB   128
#define NL   192
#define NTOK (NB * NL)   // 24576
#define DIM  512
#define HID  2048

static __device__ __forceinline__ float bf2f(u16 h) {
    union { u32 u; float f; } v; v.u = ((u32)h) << 16; return v.f;
}
static __device__ __forceinline__ u16 f2bf(float f) {
    union { float f; u32 u; } v; v.f = f;
    u32 u = v.u + 0x7FFF + ((v.u >> 16) & 1);  // RNE
    return (u16)(u >> 16);
}

// -------- all 5 weight transposes in ONE launch: f32 (K,N) -> bf16 (N,K) ----
__global__ void transpose_all(const float* __restrict__ W1, u16* __restrict__ W1T,
                              const float* __restrict__ W2, u16* __restrict__ W2T,
                              const float* __restrict__ W3, u16* __restrict__ W3T,
                              const float* __restrict__ W4, u16* __restrict__ W4T,
                              const float* __restrict__ W5, u16* __restrict__ W5T) {
    int bid = blockIdx.x;
    const float* in; u16* out; int K, N, t;
    if (bid < 1024)      { in = W1; out = W1T; K = DIM; N = HID; t = bid; }
    else if (bid < 2048) { in = W2; out = W2T; K = HID; N = DIM; t = bid - 1024; }
    else if (bid < 3072) { in = W3; out = W3T; K = DIM; N = HID; t = bid - 2048; }
    else if (bid < 4096) { in = W4; out = W4T; K = HID; N = DIM; t = bid - 3072; }
    else                 { in = W5; out = W5T; K = DIM; N = DIM; t = bid - 4096; }
    const int nx = N >> 5;
    const int n0 = (t % nx) * 32, k0 = (t / nx) * 32;
    __shared__ float tile[32][33];
    int tx = threadIdx.x & 31, ty = threadIdx.x >> 5;  // 32 x 8
#pragma unroll
    for (int i = 0; i < 4; i++)
        tile[ty + i * 8][tx] = in[(size_t)(k0 + ty + i * 8) * N + n0 + tx];
    __syncthreads();
#pragma unroll
    for (int i = 0; i < 4; i++)
        out[(size_t)(n0 + ty + i * 8) * K + k0 + tx] = f2bf(tile[tx][ty + i * 8]);
}

// -------- embedding: emb16[t=l*B+b][d] = bf16(sum of 5 f32 tables) ----
static __device__ __forceinline__ void add8f(float* acc, const float* p) {
    f32x8 v = *(const f32x8*)p;
#pragma unroll
    for (int i = 0; i < 8; i++) acc[i] += v[i];
}

__global__ void embed_kernel(const int* __restrict__ element, const int* __restrict__ aroma,
                             const int* __restrict__ charge, const int* __restrict__ segment,
                             const float* __restrict__ pe, const float* __restrict__ E_elem,
                             const float* __restrict__ E_charge, const float* __restrict__ E_aroma,
                             const float* __restrict__ E_seg,
                             u16* __restrict__ emb16) {
    int t = blockIdx.x * 4 + (threadIdx.x >> 6);  // one wave per token
    int lane = threadIdx.x & 63;
    int l = t >> 7, b = t & 127;                  // t = l*128 + b
    int d = lane * 8;
    int idx = b * NL + l;
    int e = element[idx];
    int a = aroma[idx];
    int c = charge[idx] + 6;
    int s = segment[idx];
    float acc[8] = {0, 0, 0, 0, 0, 0, 0, 0};
    add8f(acc, E_elem  + (size_t)e * DIM + d);
    add8f(acc, pe      + (size_t)l * DIM + d);
    add8f(acc, E_aroma + (size_t)a * DIM + d);
    add8f(acc, E_charge+ (size_t)c * DIM + d);
    add8f(acc, E_seg   + (size_t)s * DIM + d);
    u16x8 o16;
#pragma unroll
    for (int i = 0; i < 8; i++) o16[i] = f2bf(acc[i]);
    *(u16x8*)(emb16 + (size_t)t * DIM + d) = o16;
}

// ======== GEMM (shallow): K=512 shapes (W1/W3/W5) — r12-exact structure ======
// 2-deep double-buffer, 132 KB LDS, one vmcnt(0)+s_barrier per 64-K tile.
// Cache-hot operands (A 24 MB L3, B 2 MB L2): 1-tile lead covers ~200 cy
// latency; at nk=8 a deeper pipeline spends 25% of tiles in prologue/tail
// (r13: W1/W3 regressed 91->103 us under the 3-deep variant).
__global__ __launch_bounds__(512, 2) void gemm_bt(
    const u16* __restrict__ A, const u16* __restrict__ BT,
    const float* __restrict__ bias, const u16* __restrict__ resid16,
    u16* __restrict__ C, int M, int N, int K, int do_relu) {
    __shared__ __align__(16) u16 smem[256 * 264];   // 132 KB

    const int tid  = threadIdx.x;
    const int wave = tid >> 6;
    const int lane = tid & 63;

    const int nwg = gridDim.x;
    const int bid = blockIdx.x;
    const int wg  = ((nwg & 7) == 0) ? ((bid & 7) * (nwg >> 3) + (bid >> 3)) : bid;
    const int nt  = N >> 8;                 // N-tiles of 256
    const int m0  = (wg / nt) * 256;
    const int n0  = (wg % nt) * 256;

    const int wmh = wave >> 2;
    const int wnq = wave & 3;
    const int fr  = lane & 15;
    const int fq  = lane >> 4;
    const int ck0 = ((fq ^ (fr & 7)) * 8);
    const int ck1 = (((4 | fq) ^ (fr & 7)) * 8);

    const int sRow = tid >> 3;
    const int sChk = ((tid & 7) ^ (sRow & 7)) * 8;
    const int ldst = sRow * 64 + (tid & 7) * 8;

    const u16* Asrc = A  + (size_t)(m0 + sRow) * K + sChk;
    const u16* Bsrc = BT + (size_t)(n0 + sRow) * K + sChk;

    f32x4 acc[8][4] = {};

#define GLL(gp, lp) __builtin_amdgcn_global_load_lds(                            \
        (const __attribute__((address_space(1))) void*)(gp),                     \
        (__attribute__((address_space(3))) void*)(lp), 16, 0, 0)
#define STAGE(buf, kt) do {                                                      \
    GLL(Asrc + (size_t)(kt) * 64,                 &smem[(buf)*16384 +        ldst]); \
    GLL(Bsrc + (size_t)(kt) * 64,                 &smem[32768 + (buf)*16384 +        ldst]); \
    GLL(Asrc + (size_t)(kt) * 64 + (size_t) 64*K, &smem[(buf)*16384 +  4096 + ldst]); \
    GLL(Bsrc + (size_t)(kt) * 64 + (size_t) 64*K, &smem[32768 + (buf)*16384 +  4096 + ldst]); \
    GLL(Asrc + (size_t)(kt) * 64 + (size_t)128*K, &smem[(buf)*16384 +  8192 + ldst]); \
    GLL(Bsrc + (size_t)(kt) * 64 + (size_t)128*K, &smem[32768 + (buf)*16384 +  8192 + ldst]); \
    GLL(Asrc + (size_t)(kt) * 64 + (size_t)192*K, &smem[(buf)*16384 + 12288 + ldst]); \
    GLL(Bsrc + (size_t)(kt) * 64 + (size_t)192*K, &smem[32768 + (buf)*16384 + 12288 + ldst]); \
} while (0)

    const int nk = K >> 6;
    STAGE(0, 0);

    for (int t = 0; t < nk; ++t) {
        asm volatile("s_waitcnt vmcnt(0)\n\ts_barrier" ::: "memory");
        if (t + 1 < nk) STAGE((t + 1) & 1, t + 1);

        const u16* Ab = &smem[(t & 1) * 16384];
        const u16* Bb = &smem[32768 + (t & 1) * 16384];
#pragma unroll
        for (int s = 0; s < 2; ++s) {
            const int ck = s ? ck1 : ck0;
            bf16x8 af[8], bg[4];
#pragma unroll
            for (int i = 0; i < 8; ++i)
                af[i] = *(const bf16x8*)(&Ab[(wmh * 128 + i * 16 + fr) * 64 + ck]);
#pragma unroll
            for (int j = 0; j < 4; ++j)
                bg[j] = *(const bf16x8*)(&Bb[(wnq * 64 + j * 16 + fr) * 64 + ck]);

            __builtin_amdgcn_s_setprio(1);
#pragma unroll
            for (int i = 0; i < 8; ++i)
#pragma unroll
                for (int j = 0; j < 4; ++j)
                    acc[i][j] = __builtin_amdgcn_mfma_f32_16x16x32_bf16(
                        af[i], bg[j], acc[i][j], 0, 0, 0);
            __builtin_amdgcn_s_setprio(0);
        }
    }
#undef STAGE
#undef GLL

    __syncthreads();
#define CSTR 264
#pragma unroll
    for (int j = 0; j < 4; j++) {
        int n = n0 + wnq * 64 + j * 16 + fr;
        float bv = bias[n];
#pragma unroll
        for (int i = 0; i < 8; i++) {
#pragma unroll
            for (int r = 0; r < 4; r++) {
                int m = m0 + wmh * 128 + i * 16 + fq * 4 + r;
                float v = acc[i][j][r] + bv;
                if (do_relu) v = fmaxf(v, 0.0f);
                if (resid16) v += bf2f(resid16[(size_t)m * N + n]);
                smem[(wmh * 128 + i * 16 + fq * 4 + r) * CSTR + wnq * 64 + j * 16 + fr] = f2bf(v);
            }
        }
    }
    __syncthreads();
    {
        const int erow = tid >> 5;
        const int ecol = (tid & 31) * 8;
#pragma unroll
        for (int rr = 0; rr < 16; ++rr) {
            int row = rr * 16 + erow;
            *(u16x8*)(C + (size_t)(m0 + row) * N + n0 + ecol) =
                *(const u16x8*)(&smem[row * CSTR + ecol]);
        }
    }
#undef CSTR
}

// ======== GEMM (deep): K=2048 shapes (W2/W4) — r13 3-deep-A structure ========
// A stream = hC (100 MB, L3/HBM-miss ~900 cy): 2-tile A lead (~1300 cy) with
// counted vmcnt(4) (A(t+1) never drained in-loop); B (2 MB L2-hot) 1-tile.
// LDS: A[3]+B[2] x 32 KB = 160 KB (full pool). Proven r13: moved W2/W4 below
// the W1/W3 times.
__global__ __launch_bounds__(512, 2) void gemm_bt_deep(
    const u16* __restrict__ A, const u16* __restrict__ BT,
    const float* __restrict__ bias, const u16* __restrict__ resid16,
    u16* __restrict__ C, int M, int N, int K, int do_relu) {
    __shared__ __align__(16) u16 smem[81920];   // 160 KB

    const int tid  = threadIdx.x;
    const int wave = tid >> 6;
    const int lane = tid & 63;

    const int nwg = gridDim.x;
    const int bid = blockIdx.x;
    const int wg  = ((nwg & 7) == 0) ? ((bid & 7) * (nwg >> 3) + (bid >> 3)) : bid;
    const int nt  = N >> 8;
    const int m0  = (wg / nt) * 256;
    const int n0  = (wg % nt) * 256;

    const int wmh = wave >> 2;
    const int wnq = wave & 3;
    const int fr  = lane & 15;
    const int fq  = lane >> 4;
    const int ck0 = ((fq ^ (fr & 7)) * 8);
    const int ck1 = (((4 | fq) ^ (fr & 7)) * 8);

    const int sRow = tid >> 3;
    const int sChk = ((tid & 7) ^ (sRow & 7)) * 8;
    const int ldst = sRow * 64 + (tid & 7) * 8;

    const u16* Asrc = A  + (size_t)(m0 + sRow) * K + sChk;
    const u16* Bsrc = BT + (size_t)(n0 + sRow) * K + sChk;

    f32x4 acc[8][4] = {};

#define GLL(gp, lp) __builtin_amdgcn_global_load_lds(                            \
        (const __attribute__((address_space(1))) void*)(gp),                     \
        (__attribute__((address_space(3))) void*)(lp), 16, 0, 0)
#define STAGE_A(buf, kt) do {                                                    \
    GLL(Asrc + (size_t)(kt) * 64,                 &smem[(buf)*16384 +         ldst]); \
    GLL(Asrc + (size_t)(kt) * 64 + (size_t) 64*K, &smem[(buf)*16384 +  4096 + ldst]); \
    GLL(Asrc + (size_t)(kt) * 64 + (size_t)128*K, &smem[(buf)*16384 +  8192 + ldst]); \
    GLL(Asrc + (size_t)(kt) * 64 + (size_t)192*K, &smem[(buf)*16384 + 12288 + ldst]); \
} while (0)
#define STAGE_B(buf, kt) do {                                                    \
    GLL(Bsrc + (size_t)(kt) * 64,                 &smem[49152 + (buf)*16384 +         ldst]); \
    GLL(Bsrc + (size_t)(kt) * 64 + (size_t) 64*K, &smem[49152 + (buf)*16384 +  4096 + ldst]); \
    GLL(Bsrc + (size_t)(kt) * 64 + (size_t)128*K, &smem[49152 + (buf)*16384 +  8192 + ldst]); \
    GLL(Bsrc + (size_t)(kt) * 64 + (size_t)192*K, &smem[49152 + (buf)*16384 + 12288 + ldst]); \
} while (0)

    const int nk = K >> 6;   // 32 for our deep shapes
    STAGE_A(0, 0); STAGE_B(0, 0); STAGE_A(1, 1);

    int bt3 = 0;
    for (int t = 0; t < nk; ++t) {
        // vmcnt(4): A(t),B(t) landed; A(t+1) stays in flight (never drained).
        if (t < nk - 1)
            asm volatile("s_waitcnt vmcnt(4)\n\ts_barrier" ::: "memory");
        else
            asm volatile("s_waitcnt vmcnt(0)\n\ts_barrier" ::: "memory");
        if (t + 1 < nk) STAGE_B((t + 1) & 1, t + 1);
        if (t + 2 < nk) {
            int a3 = bt3 + 2; if (a3 >= 3) a3 -= 3;
            STAGE_A(a3, t + 2);
        }

        const u16* Ab = &smem[bt3 * 16384];
        const u16* Bb = &smem[49152 + (t & 1) * 16384];
#pragma unroll
        for (int s = 0; s < 2; ++s) {
            const int ck = s ? ck1 : ck0;
            bf16x8 af[8], bg[4];
#pragma unroll
            for (int i = 0; i < 8; ++i)
                af[i] = *(const bf16x8*)(&Ab[(wmh * 128 + i * 16 + fr) * 64 + ck]);
#pragma unroll
            for (int j = 0; j < 4; ++j)
                bg[j] = *(const bf16x8*)(&Bb[(wnq * 64 + j * 16 + fr) * 64 + ck]);

            __builtin_amdgcn_s_setprio(1);
#pragma unroll
            for (int i = 0; i < 8; ++i)
#pragma unroll
                for (int j = 0; j < 4; ++j)
                    acc[i][j] = __builtin_amdgcn_mfma_f32_16x16x32_bf16(
                        af[i], bg[j], acc[i][j], 0, 0, 0);
            __builtin_amdgcn_s_setprio(0);
        }
        bt3 = (bt3 == 2) ? 0 : bt3 + 1;
    }
#undef STAGE_A
#undef STAGE_B
#undef GLL

    __syncthreads();
#define CSTR 264
#pragma unroll
    for (int j = 0; j < 4; j++) {
        int n = n0 + wnq * 64 + j * 16 + fr;
        float bv = bias[n];
#pragma unroll
        for (int i = 0; i < 8; i++) {
#pragma unroll
            for (int r = 0; r < 4; r++) {
                int m = m0 + wmh * 128 + i * 16 + fq * 4 + r;
                float v = acc[i][j][r] + bv;
                if (do_relu) v = fmaxf(v, 0.0f);
                if (resid16) v += bf2f(resid16[(size_t)m * N + n]);
                smem[(wmh * 128 + i * 16 + fq * 4 + r) * CSTR + wnq * 64 + j * 16 + fr] = f2bf(v);
            }
        }
    }
    __syncthreads();
    {
        const int erow = tid >> 5;
        const int ecol = (tid & 31) * 8;
#pragma unroll
        for (int rr = 0; rr < 16; ++rr) {
            int row = rr * 16 + erow;
            *(u16x8*)(C + (size_t)(m0 + row) * N + n0 + ecol) =
                *(const u16x8*)(&smem[row * CSTR + ecol]);
        }
    }
#undef CSTR
}

// -------- aggregation + final residual (f32 out) --------
__global__ void agg_kernel(const u16* __restrict__ emb16, const u16* __restrict__ msg,
                           const int* __restrict__ bond, float* __restrict__ out) {
    int t = blockIdx.x * 4 + (threadIdx.x >> 6);  // one wave per token
    int lane = threadIdx.x & 63;
    int l = t >> 7, b = t & 127;
    int d = lane * 8;
    float acc[8];
    {
        u16x8 v = *(const u16x8*)(emb16 + (size_t)t * DIM + d);
#pragma unroll
        for (int i = 0; i < 8; i++) acc[i] = bf2f(v[i]);
    }
    const int* bp = bond + ((size_t)b * NL + l) * 6;
#pragma unroll
    for (int m = 0; m < 6; m++) {
        int j = bp[m];
        if (j != l) {  // wave-uniform branch
            u16x8 g = *(const u16x8*)(msg + ((size_t)j * NB + b) * DIM + d);
#pragma unroll
            for (int i = 0; i < 8; i++) acc[i] += bf2f(g[i]);
        }
    }
    f32x8 o;
#pragma unroll
    for (int i = 0; i < 8; i++) o[i] = acc[i];
    *(f32x8*)(out + (size_t)t * DIM + d) = o;
}

extern "C" void kernel_launch(void* const* d_in, const int* in_sizes, int n_in,
                              void* d_out, int out_size, void* d_ws, size_t ws_size,
                              hipStream_t stream) {
    const int* element = (const int*)d_in[0];
    const int* bond    = (const int*)d_in[1];
    const int* aroma   = (const int*)d_in[2];
    const int* charge  = (const int*)d_in[3];
    const int* segment = (const int*)d_in[4];
    const float* pe      = (const float*)d_in[5];
    const float* E_elem  = (const float*)d_in[6];
    const float* E_charge= (const float*)d_in[7];
    const float* E_aroma = (const float*)d_in[8];
    const float* E_seg   = (const float*)d_in[9];
    const float* W1 = (const float*)d_in[10];
    const float* b1 = (const float*)d_in[11];
    const float* W2 = (const float*)d_in[12];
    const float* b2 = (const float*)d_in[13];
    const float* W3 = (const float*)d_in[14];
    const float* b3 = (const float*)d_in[15];
    const float* W4 = (const float*)d_in[16];
    const float* b4 = (const float*)d_in[17];
    const float* W5 = (const float*)d_in[18];
    const float* b5 = (const float*)d_in[19];

    // dynamic ws layout — never exceed ws_size
    char* ws = (char*)d_ws;
    size_t woff = 0;
    auto take = [&](size_t bytes) -> u16* {
        u16* p = (u16*)(ws + woff);
        woff += (bytes + 255) & ~(size_t)255;
        return p;
    };
    u16* W1T = take((size_t)HID * DIM * 2);   // 2048x512 bf16
    u16* W2T = take((size_t)DIM * HID * 2);   // 512x2048
    u16* W3T = take((size_t)HID * DIM * 2);
    u16* W4T = take((size_t)DIM * HID * 2);
    u16* W5T = take((size_t)DIM * DIM * 2);
    u16* emb16 = take((size_t)NTOK * DIM * 2);  // 24 MiB
    u16* msg   = take((size_t)NTOK * DIM * 2);  // 24 MiB

    // pick largest M-chunk that fits: h(CM x HID) + xa,xb(CM x DIM), bf16.
    static const int ncs[] = {1, 2, 3, 4, 6, 8, 12, 16, 24, 32, 48, 96};
    int CM = 256;
    for (int nc : ncs) {
        int cm = NTOK / nc;
        if (cm % 256 != 0) continue;
        size_t need = woff + ((size_t)cm * HID * 2 + 256)
                           + ((size_t)cm * DIM * 2 + 256) * 2;
        if (need <= ws_size) { CM = cm; break; }
    }
    u16* hC  = take((size_t)CM * HID * 2);
    u16* xaC = take((size_t)CM * DIM * 2);
    u16* xbC = take((size_t)CM * DIM * 2);

    // all 5 weight transposes in one launch
    transpose_all<<<4352, 256, 0, stream>>>(W1, W1T, W2, W2T, W3, W3T,
                                            W4, W4T, W5, W5T);

    embed_kernel<<<NTOK / 4, 256, 0, stream>>>(element, aroma, charge, segment, pe,
                                               E_elem, E_charge, E_aroma, E_seg,
                                               emb16);

    // MLP per M-chunk: x += relu(x@W1+b1)@W2+b2 ; x += relu(x@W3+b3)@W4+b4 ; msg = x@W5+b5
    // K=512 GEMMs (W1/W3/W5): shallow 2-deep kernel; K=2048 (W2/W4): deep.
    for (int c0 = 0; c0 < NTOK; c0 += CM) {
        const u16* x16 = emb16 + (size_t)c0 * DIM;
        u16* msgC = msg + (size_t)c0 * DIM;
        int mt = CM / 256;
        gemm_bt     <<<dim3(mt * (HID / 256)), 512, 0, stream>>>(x16, W1T, b1, nullptr, hC,  CM, HID, DIM, 1);
        gemm_bt_deep<<<dim3(mt * (DIM / 256)), 512, 0, stream>>>(hC,  W2T, b2, x16,    xaC, CM, DIM, HID, 0);
        gemm_bt     <<<dim3(mt * (HID / 256)), 512, 0, stream>>>(xaC, W3T, b3, nullptr, hC,  CM, HID, DIM, 1);
        gemm_bt_deep<<<dim3(mt * (DIM / 256)), 512, 0, stream>>>(hC,  W4T, b4, xaC,    xbC, CM, DIM, HID, 0);
        gemm_bt     <<<dim3(mt * (DIM / 256)), 512, 0, stream>>>(xbC, W5T, b5, nullptr, msgC, CM, DIM, DIM, 0);
    }

    agg_kernel<<<NTOK / 4, 256, 0, stream>>>(emb16, msg, bond, (float*)d_out);
}